// Round 9
// baseline (7275.674 us; speedup 1.0000x reference)
//
#include <hip/hip_runtime.h>
#include <math.h>

// Persistent-kernel NTM, R9: two-level XCD-hierarchical barrier.
// - 128 worker blocks x 512 threads (128 rows / 128KB LDS each), no master.
// - Blocks group by runtime XCC_ID (s_getreg hwreg 20). Arrival + scalar
//   reduction use workgroup-scope global atomics = per-XCD L2 point (~0.1us)
//   instead of LLC. Last arriver of each XCD is the dynamic leader: reads the
//   L2 accumulator, sc1-publishes one packed (epoch|sum) word; the 8 leaders
//   all-to-all poll each other's words (parallel LLC loads, no master hop),
//   then release their XCD via a per-XCD sc1 go word carrying the global sum.
// - Serial chain per barrier: 2 L2 RMWs + ~3 LLC RTs (was ~5 LLC RTs).
// - Mutable cross-block data all sc1 (LLC); weights stay hot in per-XCD L2.
// - 6 barriers/step, reductions ride the barrier.

#define NBLK 128   // worker blocks
#define NTHR 512
#define Msz  16384
#define Dsz  256
#define Hsz  512
#define Isz  256
#define Tlen 128
#define RPB  128   // memory rows per worker block
#define NG   16    // rvec atomic groups
#define FSTR 32    // u32 stride per line (128B)
#define GSTR 16    // u64 stride per line (128B)

struct Params {
  const float* in[34];
  float* out;
  float* ws;
};

__device__ __forceinline__ float wred64(float v){
#pragma unroll
  for (int o = 32; o > 0; o >>= 1) v += __shfl_xor(v, o, 64);
  return v;
}
__device__ __forceinline__ float wred32(float v){
#pragma unroll
  for (int o = 16; o > 0; o >>= 1) v += __shfl_xor(v, o, 32);
  return v;
}
__device__ __forceinline__ float sigm(float x){ return 1.f / (1.f + __expf(-x)); }
__device__ __forceinline__ float softplusf(float x){ return (x > 20.f) ? x : log1pf(__expf(x)); }

// agent-scope (LLC) accessors
__device__ __forceinline__ void gstore(float* p, float v){
  __hip_atomic_store(p, v, __ATOMIC_RELAXED, __HIP_MEMORY_SCOPE_AGENT);
}
__device__ __forceinline__ float gload(const float* p){
  return __hip_atomic_load(p, __ATOMIC_RELAXED, __HIP_MEMORY_SCOPE_AGENT);
}
__device__ __forceinline__ void gstoreu(unsigned int* p, unsigned int v){
  __hip_atomic_store(p, v, __ATOMIC_RELAXED, __HIP_MEMORY_SCOPE_AGENT);
}
__device__ __forceinline__ unsigned int gloadu(const unsigned int* p){
  return __hip_atomic_load(p, __ATOMIC_RELAXED, __HIP_MEMORY_SCOPE_AGENT);
}
__device__ __forceinline__ void gstore64(unsigned long long* p, unsigned long long v){
  __hip_atomic_store(p, v, __ATOMIC_RELAXED, __HIP_MEMORY_SCOPE_AGENT);
}
__device__ __forceinline__ unsigned long long gload64(const unsigned long long* p){
  return __hip_atomic_load(p, __ATOMIC_RELAXED, __HIP_MEMORY_SCOPE_AGENT);
}
// XCD-local (per-XCD L2 point) atomics: workgroup scope -> no sc1
__device__ __forceinline__ unsigned int l2_addu(unsigned int* p, unsigned int v){
  return __hip_atomic_fetch_add(p, v, __ATOMIC_RELAXED, __HIP_MEMORY_SCOPE_WORKGROUP);
}
__device__ __forceinline__ float l2_addf(float* p, float v){
  return __hip_atomic_fetch_add(p, v, __ATOMIC_RELAXED, __HIP_MEMORY_SCOPE_WORKGROUP);
}
__device__ __forceinline__ void l2_storeu(unsigned int* p, unsigned int v){
  __hip_atomic_store(p, v, __ATOMIC_RELAXED, __HIP_MEMORY_SCOPE_WORKGROUP);
}

__global__ void __launch_bounds__(NTHR, 1)
ntm_kernel(Params P)
{
  const int b   = blockIdx.x;
  const int tid = threadIdx.x;
  const int wv  = tid >> 6;   // wave 0..7
  const int ln  = tid & 63;

  // XCD id (hwreg 20 = HW_REG_XCC_ID, offset 0, width 4) [measured: learn_hip m09]
  const unsigned x = __builtin_amdgcn_s_getreg((3 << 11) | (0 << 6) | 20) & 7u;

  // ------- inputs (setup_inputs dict order) -------
  const float* inputs  = P.in[0];
  const float* mem0    = P.in[1];
  const float* read_w0 = P.in[2];
  const float* write_w0= P.in[3];
  const float* W_ih = P.in[4];
  const float* W_hh = P.in[5];
  const float* b_ih = P.in[6];
  const float* b_hh = P.in[7];
  const float* Wo   = P.in[8];
  const float* bo   = P.in[9];
  const float* r_Wk = P.in[10]; const float* r_bk = P.in[11];
  const float* r_Wb = P.in[12]; const float* r_bb = P.in[13];
  const float* r_Wg = P.in[14]; const float* r_bg = P.in[15];
  const float* r_Ws = P.in[16]; const float* r_bs = P.in[17];
  const float* r_Wp = P.in[18]; const float* r_bp = P.in[19];
  const float* w_Wk = P.in[20]; const float* w_bk = P.in[21];
  const float* w_Wb = P.in[22]; const float* w_bb = P.in[23];
  const float* w_Wg = P.in[24]; const float* w_bg = P.in[25];
  const float* w_Ws = P.in[26]; const float* w_bs = P.in[27];
  const float* w_Wp = P.in[28]; const float* w_bp = P.in[29];
  const float* w_We = P.in[30]; const float* w_be = P.in[31];
  const float* w_Wa = P.in[32]; const float* w_ba = P.in[33];
  float* out = P.out;

  // ------- global scratch (float offsets into ws) -------
  float* ws    = P.ws;
  float* harr  = ws;                  // 1024
  float* keyw  = ws + 1024;           // 256
  float* keyr  = ws + 1280;           // 256
  float* ersv  = ws + 1536;           // 256
  float* addv  = ws + 1792;           // 256
  float* scal  = ws + 2048;           // 16
  float* eF    = ws + 2064;           // 128
  float* eL    = ws + 2192;           // 128
  float* pF    = ws + 2320;           // 128
  float* pL    = ws + 2448;           // 128 (ends 2576)
  float* parts = ws + 2592;           // NG*256 = 4096 (ends 6688)
  unsigned int* xcdCount = (unsigned int*)(ws + 6688);   // 8 lines
  unsigned int* xcdCnt   = (unsigned int*)(ws + 6944);   // 8 lines (L2-local)
  float*        xcdAcc   = ws + 7200;                    // 8 lines (L2-local)
  unsigned long long* xcdOut = (unsigned long long*)(ws + 7456); // 8 lines
  unsigned long long* goL    = (unsigned long long*)(ws + 7712); // 8 lines
  unsigned int* initFlags    = (unsigned int*)(ws + 7968);       // 128 lines
  unsigned long long* initGo = (unsigned long long*)(ws + 12064);

  // ------- LDS -------
  __shared__ float s_mem[RPB * Dsz];   // 128KB
  __shared__ float s_co[Hsz];
  __shared__ float s_a[256], s_b[256], s_c[256];
  __shared__ float s_rv[256];
  __shared__ float s_norm[RPB];
  __shared__ float s_e[RPB];
  __shared__ float s_bw[RPB];
  __shared__ float s_rw[RPB];
  __shared__ float s_ww[RPB];
  __shared__ float s_red[8];
  __shared__ float s_lg[16];
  __shared__ float s_wsum[8];
  __shared__ float s_w2[2];
  __shared__ float s_cst[4];
  __shared__ float s_pub;    // block's barrier-carried partial
  __shared__ float s_gval;   // barrier-returned global value

  unsigned int ep = 1;
  unsigned int amask = 0xff, Nx = 0;   // tid0-only

  // =========== INIT: zero + two-stage flag barrier (XCD census) ===========
  {
    if (tid == 0 && b < 8){
      gstoreu(&xcdCount[b * FSTR], 0u);
      gstoreu(&xcdCnt[b * FSTR], 0u);
      gstore(&xcdAcc[b * FSTR], 0.f);
      gstore64(&xcdOut[b * GSTR], 0ull);
      gstore64(&goL[b * GSTR], 0ull);
    }
    if (b == 0){ gstore(&harr[tid], 0.f); gstore(&harr[512 + tid], 0.f); }
    if (b < NG && tid < 256) gstore(&parts[b * 256 + tid], 0.f);
    if (tid < RPB){
      s_rw[tid] = read_w0[b * RPB + tid];
      s_ww[tid] = write_w0[b * RPB + tid];
    }
    if (tid < 4) s_cst[tid] = 0.f;
    __syncthreads();
    // stage 0: everything zeroed
    if (tid == 0){ __builtin_amdgcn_s_waitcnt(0); gstoreu(&initFlags[b * FSTR], 1u); }
    if (b == 0 && wv == 0){
      for (;;){
        unsigned a0 = gloadu(&initFlags[ln * FSTR]);
        unsigned a1 = gloadu(&initFlags[(64 + ln) * FSTR]);
        if (__all(a0 >= 1u && a1 >= 1u)) break;
        __builtin_amdgcn_s_sleep(1);
      }
      if (ln == 0) gstore64(initGo, (0xC0FFEE01ull << 32));
    }
    if (tid == 0){
      while ((unsigned)(gload64(initGo) >> 32) != 0xC0FFEE01u) __builtin_amdgcn_s_sleep(1);
    }
    __syncthreads();
    // stage 1: census
    if (tid == 0){
      (void)__hip_atomic_fetch_add(&xcdCount[x * FSTR], 1u, __ATOMIC_RELAXED, __HIP_MEMORY_SCOPE_AGENT);
      __builtin_amdgcn_s_waitcnt(0);
      gstoreu(&initFlags[b * FSTR], 2u);
    }
    if (b == 0 && wv == 0){
      for (;;){
        unsigned a0 = gloadu(&initFlags[ln * FSTR]);
        unsigned a1 = gloadu(&initFlags[(64 + ln) * FSTR]);
        if (__all(a0 >= 2u && a1 >= 2u)) break;
        __builtin_amdgcn_s_sleep(1);
      }
      if (ln == 0){
        unsigned m = 0;
        for (int y = 0; y < 8; ++y) if (gloadu(&xcdCount[y * FSTR]) > 0u) m |= (1u << y);
        gstore64(initGo, (0xC0FFEE02ull << 32) | (unsigned long long)m);
      }
    }
    if (tid == 0){
      unsigned long long pk;
      do { pk = gload64(initGo); } while ((unsigned)(pk >> 32) != 0xC0FFEE02u);
      amask = (unsigned)pk;
      Nx = gloadu(&xcdCount[x * FSTR]);
    }
    __syncthreads();
  }

  // Two-level barrier. Block partial must be in s_pub. Returns global sum.
  auto gbar = [&]()->float{
    __syncthreads();                    // phase stores drained (vmcnt 0)
    if (tid == 0){
      l2_addf(&xcdAcc[x * FSTR], s_pub);          // L2-local accumulate
      __builtin_amdgcn_s_waitcnt(0);              // acc visible at L2
      unsigned p = l2_addu(&xcdCnt[x * FSTR], 1u);
      if (p == Nx - 1u){
        // leader (last arriver): gather L2 sum, publish, all-to-all, release
        float s = l2_addf(&xcdAcc[x * FSTR], 0.f);
        l2_addf(&xcdAcc[x * FSTR], -s);           // reset acc
        l2_storeu(&xcdCnt[x * FSTR], 0u);         // reset cnt
        gstore64(&xcdOut[x * GSTR], ((unsigned long long)ep << 32) | (unsigned long long)__float_as_uint(s));
        float tot;
        for (;;){
          bool ok = true; float tt = 0.f;
#pragma unroll
          for (int y = 0; y < 8; ++y){
            if (amask & (1u << y)){
              unsigned long long pk = gload64(&xcdOut[y * GSTR]);
              if ((int)((unsigned)(pk >> 32) - ep) < 0) ok = false;
              else tt += __uint_as_float((unsigned)pk);
            }
          }
          if (ok){ tot = tt; break; }
        }
        __builtin_amdgcn_s_waitcnt(0);            // resets drained before release
        gstore64(&goL[x * GSTR], ((unsigned long long)ep << 32) | (unsigned long long)__float_as_uint(tot));
        s_gval = tot;
      } else {
        unsigned long long pk;
        do { pk = gload64(&goL[x * GSTR]); }
        while ((int)((unsigned)(pk >> 32) - ep) < 0);
        s_gval = __uint_as_float((unsigned)pk);
      }
    }
    __syncthreads();
    ++ep;
    return s_gval;
  };

  auto bred512 = [&](float v)->float{
    v = wred64(v);
    __syncthreads();
    if (ln == 0) s_red[wv] = v;
    __syncthreads();
    return s_red[0] + s_red[1] + s_red[2] + s_red[3]
         + s_red[4] + s_red[5] + s_red[6] + s_red[7];
  };

  // shift + sharpen; leaves block partial (sum of sharpened w) in s_pub
  auto shiftSharpen = [&](int si, float* s_prevw, float S){
    float g     = sigm(gload(&scal[si + 1]));
    float gamma = softplusf(gload(&scal[si + 2])) + 1.f;
    float a0 = gload(&scal[si + 3]), a1 = gload(&scal[si + 4]), a2 = gload(&scal[si + 5]);
    float mx = fmaxf(a0, fmaxf(a1, a2));
    float e0 = __expf(a0 - mx), e1 = __expf(a1 - mx), e2 = __expf(a2 - mx);
    float idn = 1.f / (e0 + e1 + e2);
    float s0 = e0 * idn, s1 = e1 * idn, s2 = e2 * idn;
    float invS = 1.f / S;
    float w = 0.f;
    if (tid < RPB){
      float gc = g * invS, gp = 1.f - g;
      float em = s_e[tid],  pm = s_prevw[tid];
      float e1n = (tid < RPB-1) ? s_e[tid+1]     : gload(&eF[(b + 1) & (NBLK-1)]);
      float p1n = (tid < RPB-1) ? s_prevw[tid+1] : gload(&pF[(b + 1) & (NBLK-1)]);
      float e2n = (tid > 0)     ? s_e[tid-1]     : gload(&eL[(b - 1) & (NBLK-1)]);
      float p2n = (tid > 0)     ? s_prevw[tid-1] : gload(&pL[(b - 1) & (NBLK-1)]);
      float gwm = gc * em  + gp * pm;
      float gw1 = gc * e1n + gp * p1n;   // roll(gw,-1)
      float gw2 = gc * e2n + gp * p2n;   // roll(gw,+1)
      float sh = s0 * gw1 + s1 * gwm + s2 * gw2;
      w = powf(sh, gamma);
      s_bw[tid] = w;
    }
    float tot = wred64(w);               // waves 0,1 hold partials
    if (ln == 0 && wv < 2) s_w2[wv] = tot;
    __syncthreads();
    if (tid == 0) s_pub = s_w2[0] + s_w2[1];
  };

  // ------- INIT2: memory rows -> LDS, norms, initial rvec partials -------
  {
#pragma unroll 1
    for (int it = 0; it < 16; ++it){
      int ml = it * 8 + wv;
      int m  = b * RPB + ml;
      float4 v = *(const float4*)(mem0 + (size_t)m * Dsz + ln * 4);
      *(float4*)(&s_mem[ml * Dsz + ln * 4]) = v;
      float n2 = wred64(v.x*v.x + v.y*v.y + v.z*v.z + v.w*v.w);
      if (ln == 0) s_norm[ml] = sqrtf(n2);
    }
    __syncthreads();
    int col = tid & 255, half = tid >> 8;
    float acc = 0.f;
#pragma unroll 1
    for (int j = half * 64; j < half * 64 + 64; ++j) acc += s_rw[j] * s_mem[j * Dsz + col];
    if (half == 0) s_a[col] = acc;
    __syncthreads();
    if (half == 1) atomicAdd(&parts[(b & (NG-1)) * 256 + col], acc + s_a[col]);
    if (tid == 0) s_pub = 0.f;
  }
  gbar();

  float Srcarry = 1.f;

  // =================== time loop ===================
  for (int t = 0; t < Tlen; ++t){
    const float* hprev = harr + (t & 1) * Hsz;
    float*       hcur  = harr + ((t + 1) & 1) * Hsz;
    const float* xt    = inputs + (size_t)t * Isz;

    // ---- A: deferred rw/rvec normalize; LSTM gates (block owns units 4b..4b+3) ----
    {
      float SrDiv = (t == 0) ? 1.f : (Srcarry + 1e-8f);
      if (t > 0 && tid < RPB) s_rw[tid] = s_bw[tid] / SrDiv;
      s_co[tid] = gload(&hprev[tid]);
      if (tid < 256){
        s_a[tid] = xt[tid];
        float rvv = 0.f;
#pragma unroll
        for (int p = 0; p < NG; ++p) rvv += gload(&parts[p * 256 + tid]);
        s_rv[tid] = rvv / SrDiv;
      }
      __syncthreads();
      int dd = tid >> 5;          // 0..15: gate = dd>>2, unit = dd&3
      int l  = tid & 31;
      int jj = (b << 2) + (dd & 3);
      int g  = dd >> 2;
      int r  = g * Hsz + jj;
      const float* wi = W_ih + (size_t)r * (Isz + Dsz);
      const float* wh = W_hh + (size_t)r * Hsz;
      float acc = 0.f;
#pragma unroll
      for (int it = 0; it < 4; ++it){
        int k = it * 128 + l * 4;
        float4 a  = *(const float4*)(wi + k);
        float4 xx = (k < Isz) ? *(const float4*)(&s_a[k]) : *(const float4*)(&s_rv[k - Isz]);
        acc += a.x*xx.x + a.y*xx.y + a.z*xx.z + a.w*xx.w;
        float4 hw = *(const float4*)(wh + k);
        float4 hv = *(const float4*)(&s_co[k]);
        acc += hw.x*hv.x + hw.y*hv.y + hw.z*hv.z + hw.w*hv.w;
      }
      acc = wred32(acc);
      if (l == 0) s_lg[dd] = acc + b_ih[r] + b_hh[r];
      __syncthreads();
      if (tid < 4){
        int j = (b << 2) + tid;
        float iv = s_lg[tid], fv = s_lg[4 + tid], gv = s_lg[8 + tid], ov = s_lg[12 + tid];
        float cn = sigm(fv) * s_cst[tid] + sigm(iv) * tanhf(gv);
        s_cst[tid] = cn;
        gstore(&hcur[j], sigm(ov) * tanhf(cn));
      }
      if (tid == 0) s_pub = 0.f;
    }
    gbar();

    // ---- C: head projections + output GEMV (11 slots/block); zero rvec parts ----
    {
      s_co[tid] = gload(&hcur[tid]);
      if (b < NG && tid < 256) gstore(&parts[b * 256 + tid], 0.f);
      __syncthreads();
#pragma unroll
      for (int qi = 0; qi < 2; ++qi){
        int idx = qi * 8 + wv;        // 0..15
        int slot = b * 11 + idx;
        if (idx < 11 && slot < 1292){
          const float* Wrow = nullptr; float bias = 0.f; int len = 512;
          float* dst = nullptr; bool act = false; bool plain = false;
          if (slot < 256){ Wrow = w_Wk + (size_t)slot * Hsz; bias = w_bk[slot]; dst = keyw + slot; }
          else if (slot < 512){ int i = slot - 256; Wrow = w_We + (size_t)i * Hsz; bias = w_be[i]; dst = ersv + i; act = true; }
          else if (slot < 768){ int i = slot - 512; Wrow = w_Wa + (size_t)i * Hsz; bias = w_ba[i]; dst = addv + i; }
          else if (slot < 1024){ int i = slot - 768; Wrow = r_Wk + (size_t)i * Hsz; bias = r_bk[i]; dst = keyr + i; }
          else if (slot < 1280){ int i = slot - 1024; Wrow = Wo + (size_t)i * (Hsz + Dsz); bias = bo[i]; len = 768; dst = out + (size_t)t * Isz + i; plain = true; }
          else {
            int i = slot - 1280;
            int ii = (i >= 6) ? i - 6 : i;
            bool rh = (i >= 6);
            const float *Wt, *bt; int row = 0;
            if (ii == 0){ Wt = rh ? r_Wb : w_Wb; bt = rh ? r_bb : w_bb; }
            else if (ii == 1){ Wt = rh ? r_Wg : w_Wg; bt = rh ? r_bg : w_bg; }
            else if (ii == 2){ Wt = rh ? r_Wp : w_Wp; bt = rh ? r_bp : w_bp; }
            else { Wt = rh ? r_Ws : w_Ws; bt = rh ? r_bs : w_bs; row = ii - 3; }
            Wrow = Wt + (size_t)row * Hsz; bias = bt[row]; dst = scal + i;
          }
          float acc = 0.f;
          if (len == 512){
            int k = ln * 8;
            float4 a0 = *(const float4*)(Wrow + k);
            float4 a1 = *(const float4*)(Wrow + k + 4);
            float4 c0 = *(const float4*)(&s_co[k]);
            float4 c1 = *(const float4*)(&s_co[k + 4]);
            acc = a0.x*c0.x + a0.y*c0.y + a0.z*c0.z + a0.w*c0.w
                + a1.x*c1.x + a1.y*c1.y + a1.z*c1.z + a1.w*c1.w;
          } else {
#pragma unroll 1
            for (int kk = ln; kk < 768; kk += 64){
              float xv = (kk < Hsz) ? s_co[kk] : s_rv[kk - Hsz];
              acc += Wrow[kk] * xv;
            }
          }
          acc = wred64(acc);
          if (ln == 0){
            float v = acc + bias;
            if (act) v = sigm(v);
            if (plain) *dst = v; else gstore(dst, v);
          }
        }
      }
      if (tid == 0) s_pub = 0.f;
    }
    gbar();

    // ---- D: write-head content scores; block e-sum partial rides the barrier ----
    {
      if (tid < 256) s_a[tid] = gload(&keyw[tid]);
      float nk2 = bred512((tid < 256) ? s_a[tid] * s_a[tid] : 0.f);
      float beta  = softplusf(gload(&scal[0]));
      float invbk = beta / fmaxf(sqrtf(nk2), 1e-12f);
      float esum = 0.f;
#pragma unroll 1
      for (int it = 0; it < 16; ++it){
        int ml = it * 8 + wv;
        float4 v  = *(const float4*)(&s_mem[ml * Dsz + ln * 4]);
        float4 kv = *(const float4*)(&s_a[ln * 4]);
        float d = wred64(v.x*kv.x + v.y*kv.y + v.z*kv.z + v.w*kv.w);
        float score = d * invbk / fmaxf(s_norm[ml], 1e-12f);
        float e = __expf(score - beta);
        if (ln == 0){ s_e[ml] = e; esum += e; }
      }
      if (ln == 0) s_wsum[wv] = esum;
      __syncthreads();
      if (tid == 0){
        float tot = 0.f;
#pragma unroll
        for (int k = 0; k < 8; ++k) tot += s_wsum[k];
        s_pub = tot;
        gstore(&eF[b], s_e[0]);  gstore(&eL[b], s_e[RPB-1]);
        gstore(&pF[b], s_ww[0]); gstore(&pL[b], s_ww[RPB-1]);
      }
    }
    float S_w = gbar();   // carried: write-head softmax denom

    // ---- F: write-head interpolate + shift + sharpen ----
    shiftSharpen(0, s_ww, S_w);
    float Sw = gbar();    // carried: write-weight normalizer

    // ---- H: normalize ww, memory update, new norms + read scores ----
    {
      if (tid < 256){ s_a[tid] = gload(&ersv[tid]); s_b[tid] = gload(&addv[tid]); s_c[tid] = gload(&keyr[tid]); }
      float nk2 = bred512((tid < 256) ? s_c[tid] * s_c[tid] : 0.f);
      float beta  = softplusf(gload(&scal[6]));
      float invbk = beta / fmaxf(sqrtf(nk2), 1e-12f);
      float invSw = 1.f / (Sw + 1e-8f);
      if (tid < RPB) s_ww[tid] = s_bw[tid] * invSw;
      float esum = 0.f;
#pragma unroll 1
      for (int it = 0; it < 16; ++it){
        int ml = it * 8 + wv;
        float wwm = s_bw[ml] * invSw;
        int off = ml * Dsz + ln * 4;
        float4 mv = *(const float4*)(&s_mem[off]);
        float4 er = *(const float4*)(&s_a[ln * 4]);
        float4 ad = *(const float4*)(&s_b[ln * 4]);
        float4 kr = *(const float4*)(&s_c[ln * 4]);
        float4 nv;
        nv.x = mv.x * (1.f - wwm * er.x) + wwm * ad.x;
        nv.y = mv.y * (1.f - wwm * er.y) + wwm * ad.y;
        nv.z = mv.z * (1.f - wwm * er.z) + wwm * ad.z;
        nv.w = mv.w * (1.f - wwm * er.w) + wwm * ad.w;
        *(float4*)(&s_mem[off]) = nv;
        float n2 = nv.x*nv.x + nv.y*nv.y + nv.z*nv.z + nv.w*nv.w;
        float dt = nv.x*kr.x + nv.y*kr.y + nv.z*kr.z + nv.w*kr.w;
        n2 = wred64(n2);
        dt = wred64(dt);
        float nr = sqrtf(n2);
        if (ln == 0) s_norm[ml] = nr;
        float score = dt * invbk / fmaxf(nr, 1e-12f);
        float e = __expf(score - beta);
        if (ln == 0){ s_e[ml] = e; esum += e; }
      }
      if (ln == 0) s_wsum[wv] = esum;
      __syncthreads();
      if (tid == 0){
        float tot = 0.f;
#pragma unroll
        for (int k = 0; k < 8; ++k) tot += s_wsum[k];
        s_pub = tot;
        gstore(&eF[b], s_e[0]);  gstore(&eL[b], s_e[RPB-1]);
        gstore(&pF[b], s_rw[0]); gstore(&pL[b], s_rw[RPB-1]);
      }
    }
    float S_r = gbar();   // carried: read-head softmax denom

    // ---- J: read-head shift+sharpen; UNNORMALIZED rvec partials ----
    {
      shiftSharpen(6, s_rw, S_r);
      __syncthreads();
      int col = tid & 255, half = tid >> 8;
      float acc = 0.f;
#pragma unroll 1
      for (int j = half * 64; j < half * 64 + 64; ++j) acc += s_bw[j] * s_mem[j * Dsz + col];
      if (half == 0) s_a[col] = acc;
      __syncthreads();
      if (half == 1) atomicAdd(&parts[(b & (NG-1)) * 256 + col], acc + s_a[col]);
    }
    Srcarry = gbar();     // carried: read-weight normalizer for A(t+1)
  }
}

extern "C" void kernel_launch(void* const* d_in, const int* in_sizes, int n_in,
                              void* d_out, int out_size, void* d_ws, size_t ws_size,
                              hipStream_t stream)
{
  (void)in_sizes; (void)out_size;
  if (n_in < 34) return;
  if (ws_size < (size_t)65536) return;   // ~49KB scratch needed
  Params P;
  for (int i = 0; i < 34; ++i) P.in[i] = (const float*)d_in[i];
  P.out = (float*)d_out;
  P.ws  = (float*)d_ws;
  hipLaunchKernelGGL(ntm_kernel, dim3(NBLK), dim3(NTHR), 0, stream, P);
}

// Round 10
// 5379.670 us; speedup vs baseline: 1.3524x; 1.3524x over previous
//
#include <hip/hip_runtime.h>
#include <math.h>

// Persistent-kernel NTM, R10: all-to-all flag barrier (shortest serial chain).
// - 128 worker blocks x 512 threads (128 rows / 128KB LDS each). No master.
// - Barrier: each block's tid0 stores epoch to its OWN 128B-padded flag line;
//   wave 0 of EVERY block polls all 128 flags (2 lanes-loads/lane). Detection
//   happens within ~1 poll round of the last arrival -- no master hop, no go
//   word. 16K poll requests/round spread over 128 private lines (no convoy).
// - Carried reductions: after detection, wave 0 gathers psA/psB (128 floats,
//   2 sc1 loads/lane + wred64) itself.
// - No fences: mutable cross-block data all sc1 (LLC-coherent); weights stay
//   hot in per-XCD L2. 6 barriers/step.
// - Phase C slots rebalanced: slot = q*128 + b (equal work all blocks).

#define NBLK 128   // worker blocks
#define NTHR 512
#define Msz  16384
#define Dsz  256
#define Hsz  512
#define Isz  256
#define Tlen 128
#define RPB  128   // memory rows per worker block
#define NG   16    // rvec atomic groups
#define FSTR 32    // u32 stride per line (128B)

struct Params {
  const float* in[34];
  float* out;
  float* ws;
};

__device__ __forceinline__ float wred64(float v){
#pragma unroll
  for (int o = 32; o > 0; o >>= 1) v += __shfl_xor(v, o, 64);
  return v;
}
__device__ __forceinline__ float wred32(float v){
#pragma unroll
  for (int o = 16; o > 0; o >>= 1) v += __shfl_xor(v, o, 32);
  return v;
}
__device__ __forceinline__ float sigm(float x){ return 1.f / (1.f + __expf(-x)); }
__device__ __forceinline__ float softplusf(float x){ return (x > 20.f) ? x : log1pf(__expf(x)); }

// agent-scope (LLC) accessors for mutable cross-block data
__device__ __forceinline__ void gstore(float* p, float v){
  __hip_atomic_store(p, v, __ATOMIC_RELAXED, __HIP_MEMORY_SCOPE_AGENT);
}
__device__ __forceinline__ float gload(const float* p){
  return __hip_atomic_load(p, __ATOMIC_RELAXED, __HIP_MEMORY_SCOPE_AGENT);
}
__device__ __forceinline__ void gstoreu(unsigned int* p, unsigned int v){
  __hip_atomic_store(p, v, __ATOMIC_RELAXED, __HIP_MEMORY_SCOPE_AGENT);
}
__device__ __forceinline__ unsigned int gloadu(const unsigned int* p){
  return __hip_atomic_load(p, __ATOMIC_RELAXED, __HIP_MEMORY_SCOPE_AGENT);
}

__global__ void __launch_bounds__(NTHR, 1)
ntm_kernel(Params P)
{
  const int b   = blockIdx.x;
  const int tid = threadIdx.x;
  const int wv  = tid >> 6;   // wave 0..7
  const int ln  = tid & 63;

  // ------- inputs (setup_inputs dict order) -------
  const float* inputs  = P.in[0];
  const float* mem0    = P.in[1];
  const float* read_w0 = P.in[2];
  const float* write_w0= P.in[3];
  const float* W_ih = P.in[4];
  const float* W_hh = P.in[5];
  const float* b_ih = P.in[6];
  const float* b_hh = P.in[7];
  const float* Wo   = P.in[8];
  const float* bo   = P.in[9];
  const float* r_Wk = P.in[10]; const float* r_bk = P.in[11];
  const float* r_Wb = P.in[12]; const float* r_bb = P.in[13];
  const float* r_Wg = P.in[14]; const float* r_bg = P.in[15];
  const float* r_Ws = P.in[16]; const float* r_bs = P.in[17];
  const float* r_Wp = P.in[18]; const float* r_bp = P.in[19];
  const float* w_Wk = P.in[20]; const float* w_bk = P.in[21];
  const float* w_Wb = P.in[22]; const float* w_bb = P.in[23];
  const float* w_Wg = P.in[24]; const float* w_bg = P.in[25];
  const float* w_Ws = P.in[26]; const float* w_bs = P.in[27];
  const float* w_Wp = P.in[28]; const float* w_bp = P.in[29];
  const float* w_We = P.in[30]; const float* w_be = P.in[31];
  const float* w_Wa = P.in[32]; const float* w_ba = P.in[33];
  float* out = P.out;

  // ------- global scratch (float offsets) -------
  float* ws    = P.ws;
  float* harr  = ws;                  // 1024
  float* keyw  = ws + 1024;           // 256
  float* keyr  = ws + 1280;           // 256
  float* ersv  = ws + 1536;           // 256
  float* addv  = ws + 1792;           // 256
  float* scal  = ws + 2048;           // 16
  float* psA   = ws + 2064;           // 128
  float* psB   = ws + 2192;           // 128
  float* eF    = ws + 2320;           // 128
  float* eL    = ws + 2448;           // 128
  float* pF    = ws + 2576;           // 128
  float* pL    = ws + 2704;           // 128 (ends 2832)
  float* parts = ws + 2848;           // NG*256 = 4096 (ends 6944)
  unsigned int* flags = (unsigned int*)(ws + 6944); // 128 x FSTR u32, 128B-aligned

  // ------- LDS -------
  __shared__ float s_mem[RPB * Dsz];   // 128KB
  __shared__ float s_co[Hsz];
  __shared__ float s_a[256], s_b[256], s_c[256];
  __shared__ float s_rv[256];
  __shared__ float s_norm[RPB];
  __shared__ float s_e[RPB];
  __shared__ float s_bw[RPB];
  __shared__ float s_rw[RPB];
  __shared__ float s_ww[RPB];
  __shared__ float s_red[8];
  __shared__ float s_lg[16];
  __shared__ float s_wsum[8];
  __shared__ float s_w2[2];
  __shared__ float s_cst[4];
  __shared__ float s_gval;

  unsigned int ep = 1;

  // ------- INIT1: zero own flag + shared state (ws poisoned 0xAA each launch).
  // Poison reads as "not arrived" ((int)(0xAAAAAAAA - ep) < 0), so no handshake
  // needed: first barrier resolves once every block has zeroed+arrived.
  {
    if (tid == 0) gstoreu(&flags[b * FSTR], 0u);
    if (b == 0){ gstore(&harr[tid], 0.f); gstore(&harr[512 + tid], 0.f); }
    if (b < NG && tid < 256) gstore(&parts[b * 256 + tid], 0.f);
    if (tid < RPB){
      s_rw[tid] = read_w0[b * RPB + tid];
      s_ww[tid] = write_w0[b * RPB + tid];
    }
    if (tid < 4) s_cst[tid] = 0.f;
  }

  // All-to-all barrier. which: 0=none, 1=carry sum(psA), 2=carry sum(psB).
  auto gbar = [&](int which)->float{
    __syncthreads();                   // drain: all sc1 stores at LLC
    if (tid == 0) gstoreu(&flags[b * FSTR], ep);
    if (wv == 0){
      for (;;){
        unsigned a0 = gloadu(&flags[ln * FSTR]);
        unsigned a1 = gloadu(&flags[(64 + ln) * FSTR]);
        bool ok = ((int)(a0 - ep) >= 0) && ((int)(a1 - ep) >= 0);
        if (__all(ok)) break;
        __builtin_amdgcn_s_sleep(1);
      }
      if (which != 0){
        const float* ps = (which == 1) ? psA : psB;
        float v = gload(&ps[ln]) + gload(&ps[64 + ln]);
        v = wred64(v);
        if (ln == 0) s_gval = v;
      }
    }
    __syncthreads();
    ++ep;
    return s_gval;
  };

  auto bred512 = [&](float v)->float{
    v = wred64(v);
    __syncthreads();
    if (ln == 0) s_red[wv] = v;
    __syncthreads();
    return s_red[0] + s_red[1] + s_red[2] + s_red[3]
         + s_red[4] + s_red[5] + s_red[6] + s_red[7];
  };

  // shift + sharpen; publishes block partial to psB[b]
  auto shiftSharpen = [&](int si, float* s_prevw, float S){
    float g     = sigm(gload(&scal[si + 1]));
    float gamma = softplusf(gload(&scal[si + 2])) + 1.f;
    float a0 = gload(&scal[si + 3]), a1 = gload(&scal[si + 4]), a2 = gload(&scal[si + 5]);
    float mx = fmaxf(a0, fmaxf(a1, a2));
    float e0 = __expf(a0 - mx), e1 = __expf(a1 - mx), e2 = __expf(a2 - mx);
    float idn = 1.f / (e0 + e1 + e2);
    float s0 = e0 * idn, s1 = e1 * idn, s2 = e2 * idn;
    float invS = 1.f / S;
    float w = 0.f;
    if (tid < RPB){
      float gc = g * invS, gp = 1.f - g;
      float em = s_e[tid],  pm = s_prevw[tid];
      float e1n = (tid < RPB-1) ? s_e[tid+1]     : gload(&eF[(b + 1) & (NBLK-1)]);
      float p1n = (tid < RPB-1) ? s_prevw[tid+1] : gload(&pF[(b + 1) & (NBLK-1)]);
      float e2n = (tid > 0)     ? s_e[tid-1]     : gload(&eL[(b - 1) & (NBLK-1)]);
      float p2n = (tid > 0)     ? s_prevw[tid-1] : gload(&pL[(b - 1) & (NBLK-1)]);
      float gwm = gc * em  + gp * pm;
      float gw1 = gc * e1n + gp * p1n;   // roll(gw,-1)
      float gw2 = gc * e2n + gp * p2n;   // roll(gw,+1)
      float sh = s0 * gw1 + s1 * gwm + s2 * gw2;
      w = powf(sh, gamma);
      s_bw[tid] = w;
    }
    float tot = wred64(w);               // waves 0,1 hold partials
    if (ln == 0 && wv < 2) s_w2[wv] = tot;
    __syncthreads();
    if (tid == 0) gstore(&psB[b], s_w2[0] + s_w2[1]);
  };

  // ------- INIT2: memory rows -> LDS, norms, initial rvec partials -------
  {
#pragma unroll 1
    for (int it = 0; it < 16; ++it){
      int ml = it * 8 + wv;
      int m  = b * RPB + ml;
      float4 v = *(const float4*)(mem0 + (size_t)m * Dsz + ln * 4);
      *(float4*)(&s_mem[ml * Dsz + ln * 4]) = v;
      float n2 = wred64(v.x*v.x + v.y*v.y + v.z*v.z + v.w*v.w);
      if (ln == 0) s_norm[ml] = sqrtf(n2);
    }
    __syncthreads();
    int col = tid & 255, half = tid >> 8;
    float acc = 0.f;
#pragma unroll 1
    for (int j = half * 64; j < half * 64 + 64; ++j) acc += s_rw[j] * s_mem[j * Dsz + col];
    if (half == 0) s_a[col] = acc;
    __syncthreads();
    if (half == 1) atomicAdd(&parts[(b & (NG-1)) * 256 + col], acc + s_a[col]);
  }
  gbar(0);

  float Srcarry = 1.f;

  // =================== time loop ===================
  for (int t = 0; t < Tlen; ++t){
    const float* hprev = harr + (t & 1) * Hsz;
    float*       hcur  = harr + ((t + 1) & 1) * Hsz;
    const float* xt    = inputs + (size_t)t * Isz;

    // ---- A: deferred rw/rvec normalize; LSTM gates (block owns units 4b..4b+3) ----
    {
      float SrDiv = (t == 0) ? 1.f : (Srcarry + 1e-8f);
      if (t > 0 && tid < RPB) s_rw[tid] = s_bw[tid] / SrDiv;
      s_co[tid] = gload(&hprev[tid]);
      if (tid < 256){
        s_a[tid] = xt[tid];
        float rvv = 0.f;
#pragma unroll
        for (int p = 0; p < NG; ++p) rvv += gload(&parts[p * 256 + tid]);
        s_rv[tid] = rvv / SrDiv;
      }
      __syncthreads();
      int dd = tid >> 5;          // 0..15: gate = dd>>2, unit = dd&3
      int l  = tid & 31;
      int jj = (b << 2) + (dd & 3);
      int g  = dd >> 2;
      int r  = g * Hsz + jj;
      const float* wi = W_ih + (size_t)r * (Isz + Dsz);
      const float* wh = W_hh + (size_t)r * Hsz;
      float acc = 0.f;
#pragma unroll
      for (int it = 0; it < 4; ++it){
        int k = it * 128 + l * 4;
        float4 a  = *(const float4*)(wi + k);
        float4 xx = (k < Isz) ? *(const float4*)(&s_a[k]) : *(const float4*)(&s_rv[k - Isz]);
        acc += a.x*xx.x + a.y*xx.y + a.z*xx.z + a.w*xx.w;
        float4 hw = *(const float4*)(wh + k);
        float4 hv = *(const float4*)(&s_co[k]);
        acc += hw.x*hv.x + hw.y*hv.y + hw.z*hv.z + hw.w*hv.w;
      }
      acc = wred32(acc);
      if (l == 0) s_lg[dd] = acc + b_ih[r] + b_hh[r];
      __syncthreads();
      if (tid < 4){
        int j = (b << 2) + tid;
        float iv = s_lg[tid], fv = s_lg[4 + tid], gv = s_lg[8 + tid], ov = s_lg[12 + tid];
        float cn = sigm(fv) * s_cst[tid] + sigm(iv) * tanhf(gv);
        s_cst[tid] = cn;
        gstore(&hcur[j], sigm(ov) * tanhf(cn));
      }
    }
    gbar(0);

    // ---- C: head projections + output GEMV (slot = q*128 + b, balanced); zero parts ----
    {
      s_co[tid] = gload(&hcur[tid]);
      if (b < NG && tid < 256) gstore(&parts[b * 256 + tid], 0.f);
      __syncthreads();
#pragma unroll
      for (int qi = 0; qi < 2; ++qi){
        int q = qi * 8 + wv;          // 0..15
        int slot = q * 128 + b;
        if (q < 11 && slot < 1292){
          const float* Wrow = nullptr; float bias = 0.f; int len = 512;
          float* dst = nullptr; bool act = false; bool plain = false;
          if (slot < 256){ Wrow = w_Wk + (size_t)slot * Hsz; bias = w_bk[slot]; dst = keyw + slot; }
          else if (slot < 512){ int i = slot - 256; Wrow = w_We + (size_t)i * Hsz; bias = w_be[i]; dst = ersv + i; act = true; }
          else if (slot < 768){ int i = slot - 512; Wrow = w_Wa + (size_t)i * Hsz; bias = w_ba[i]; dst = addv + i; }
          else if (slot < 1024){ int i = slot - 768; Wrow = r_Wk + (size_t)i * Hsz; bias = r_bk[i]; dst = keyr + i; }
          else if (slot < 1280){ int i = slot - 1024; Wrow = Wo + (size_t)i * (Hsz + Dsz); bias = bo[i]; len = 768; dst = out + (size_t)t * Isz + i; plain = true; }
          else {
            int i = slot - 1280;
            int ii = (i >= 6) ? i - 6 : i;
            bool rh = (i >= 6);
            const float *Wt, *bt; int row = 0;
            if (ii == 0){ Wt = rh ? r_Wb : w_Wb; bt = rh ? r_bb : w_bb; }
            else if (ii == 1){ Wt = rh ? r_Wg : w_Wg; bt = rh ? r_bg : w_bg; }
            else if (ii == 2){ Wt = rh ? r_Wp : w_Wp; bt = rh ? r_bp : w_bp; }
            else { Wt = rh ? r_Ws : w_Ws; bt = rh ? r_bs : w_bs; row = ii - 3; }
            Wrow = Wt + (size_t)row * Hsz; bias = bt[row]; dst = scal + i;
          }
          float acc = 0.f;
          if (len == 512){
            int k = ln * 8;
            float4 a0 = *(const float4*)(Wrow + k);
            float4 a1 = *(const float4*)(Wrow + k + 4);
            float4 c0 = *(const float4*)(&s_co[k]);
            float4 c1 = *(const float4*)(&s_co[k + 4]);
            acc = a0.x*c0.x + a0.y*c0.y + a0.z*c0.z + a0.w*c0.w
                + a1.x*c1.x + a1.y*c1.y + a1.z*c1.z + a1.w*c1.w;
          } else {
#pragma unroll 1
            for (int kk = ln; kk < 768; kk += 64){
              float xv = (kk < Hsz) ? s_co[kk] : s_rv[kk - Hsz];
              acc += Wrow[kk] * xv;
            }
          }
          acc = wred64(acc);
          if (ln == 0){
            float v = acc + bias;
            if (act) v = sigm(v);
            if (plain) *dst = v; else gstore(dst, v);
          }
        }
      }
    }
    gbar(0);

    // ---- D: write-head content scores; publish psA + boundaries ----
    {
      if (tid < 256) s_a[tid] = gload(&keyw[tid]);
      float nk2 = bred512((tid < 256) ? s_a[tid] * s_a[tid] : 0.f);
      float beta  = softplusf(gload(&scal[0]));
      float invbk = beta / fmaxf(sqrtf(nk2), 1e-12f);
      float esum = 0.f;
#pragma unroll 1
      for (int it = 0; it < 16; ++it){
        int ml = it * 8 + wv;
        float4 v  = *(const float4*)(&s_mem[ml * Dsz + ln * 4]);
        float4 kv = *(const float4*)(&s_a[ln * 4]);
        float d = wred64(v.x*kv.x + v.y*kv.y + v.z*kv.z + v.w*kv.w);
        float score = d * invbk / fmaxf(s_norm[ml], 1e-12f);
        float e = __expf(score - beta);
        if (ln == 0){ s_e[ml] = e; esum += e; }
      }
      if (ln == 0) s_wsum[wv] = esum;
      __syncthreads();
      if (tid == 0){
        float tot = 0.f;
#pragma unroll
        for (int k = 0; k < 8; ++k) tot += s_wsum[k];
        gstore(&psA[b], tot);
        gstore(&eF[b], s_e[0]);  gstore(&eL[b], s_e[RPB-1]);
        gstore(&pF[b], s_ww[0]); gstore(&pL[b], s_ww[RPB-1]);
      }
    }
    float S_w = gbar(1);   // carried: write-head softmax denom

    // ---- F: write-head interpolate + shift + sharpen ----
    shiftSharpen(0, s_ww, S_w);
    float Sw = gbar(2);    // carried: write-weight normalizer

    // ---- H: normalize ww, memory update, new norms + read scores ----
    {
      if (tid < 256){ s_a[tid] = gload(&ersv[tid]); s_b[tid] = gload(&addv[tid]); s_c[tid] = gload(&keyr[tid]); }
      float nk2 = bred512((tid < 256) ? s_c[tid] * s_c[tid] : 0.f);
      float beta  = softplusf(gload(&scal[6]));
      float invbk = beta / fmaxf(sqrtf(nk2), 1e-12f);
      float invSw = 1.f / (Sw + 1e-8f);
      if (tid < RPB) s_ww[tid] = s_bw[tid] * invSw;
      float esum = 0.f;
#pragma unroll 1
      for (int it = 0; it < 16; ++it){
        int ml = it * 8 + wv;
        float wwm = s_bw[ml] * invSw;
        int off = ml * Dsz + ln * 4;
        float4 mv = *(const float4*)(&s_mem[off]);
        float4 er = *(const float4*)(&s_a[ln * 4]);
        float4 ad = *(const float4*)(&s_b[ln * 4]);
        float4 kr = *(const float4*)(&s_c[ln * 4]);
        float4 nv;
        nv.x = mv.x * (1.f - wwm * er.x) + wwm * ad.x;
        nv.y = mv.y * (1.f - wwm * er.y) + wwm * ad.y;
        nv.z = mv.z * (1.f - wwm * er.z) + wwm * ad.z;
        nv.w = mv.w * (1.f - wwm * er.w) + wwm * ad.w;
        *(float4*)(&s_mem[off]) = nv;
        float n2 = nv.x*nv.x + nv.y*nv.y + nv.z*nv.z + nv.w*nv.w;
        float dt = nv.x*kr.x + nv.y*kr.y + nv.z*kr.z + nv.w*kr.w;
        n2 = wred64(n2);
        dt = wred64(dt);
        float nr = sqrtf(n2);
        if (ln == 0) s_norm[ml] = nr;
        float score = dt * invbk / fmaxf(nr, 1e-12f);
        float e = __expf(score - beta);
        if (ln == 0){ s_e[ml] = e; esum += e; }
      }
      if (ln == 0) s_wsum[wv] = esum;
      __syncthreads();
      if (tid == 0){
        float tot = 0.f;
#pragma unroll
        for (int k = 0; k < 8; ++k) tot += s_wsum[k];
        gstore(&psA[b], tot);
        gstore(&eF[b], s_e[0]);  gstore(&eL[b], s_e[RPB-1]);
        gstore(&pF[b], s_rw[0]); gstore(&pL[b], s_rw[RPB-1]);
      }
    }
    float S_r = gbar(1);   // carried: read-head softmax denom

    // ---- J: read-head shift+sharpen; UNNORMALIZED rvec partials ----
    {
      shiftSharpen(6, s_rw, S_r);
      __syncthreads();
      int col = tid & 255, half = tid >> 8;
      float acc = 0.f;
#pragma unroll 1
      for (int j = half * 64; j < half * 64 + 64; ++j) acc += s_bw[j] * s_mem[j * Dsz + col];
      if (half == 0) s_a[col] = acc;
      __syncthreads();
      if (half == 1) atomicAdd(&parts[(b & (NG-1)) * 256 + col], acc + s_a[col]);
    }
    Srcarry = gbar(2);     // carried: read-weight normalizer for A(t+1)
  }
}

extern "C" void kernel_launch(void* const* d_in, const int* in_sizes, int n_in,
                              void* d_out, int out_size, void* d_ws, size_t ws_size,
                              hipStream_t stream)
{
  (void)in_sizes; (void)out_size;
  if (n_in < 34) return;
  if (ws_size < (size_t)65536) return;   // ~44KB scratch needed
  Params P;
  for (int i = 0; i < 34; ++i) P.in[i] = (const float*)d_in[i];
  P.out = (float*)d_out;
  P.ws  = (float*)d_ws;
  hipLaunchKernelGGL(ntm_kernel, dim3(NBLK), dim3(NTHR), 0, stream, P);
}

// Round 11
// 4988.557 us; speedup vs baseline: 1.4585x; 1.0784x over previous
//
#include <hip/hip_runtime.h>
#include <math.h>

// Persistent-kernel NTM, R11: cut the serial chain, not the topology.
// - lbar(): lgkmcnt-only block barrier (no vmcnt drain of in-flight sc1 stores).
//   Full __syncthreads drain only in A, C (bulk stores) and J (atomics).
// - pub64 barriers: arrival word = (epoch|value); reduction rides the poll.
//   Per-phase pub arrays (reuse distance = 1 step -> race-free value capture).
// - Boundary e/prevw values are self-tagged u64s -> D/F/H phases need NO drain.
// - H's bulk inputs prefetched by waves 4-7 during F. Hot-spin polls.
// - parts double-buffered (D zeroes next buffer; J's full drain orders it).

#define NBLK 128
#define NTHR 512
#define Msz  16384
#define Dsz  256
#define Hsz  512
#define Isz  256
#define Tlen 128
#define RPB  128
#define NG   16
#define PUBSTR 8   // u64 stride (64B) for pub arrays

struct Params { const float* in[34]; float* out; float* ws; };

__device__ __forceinline__ float wred64(float v){
#pragma unroll
  for (int o = 32; o > 0; o >>= 1) v += __shfl_xor(v, o, 64);
  return v;
}
__device__ __forceinline__ float wred32(float v){
#pragma unroll
  for (int o = 16; o > 0; o >>= 1) v += __shfl_xor(v, o, 32);
  return v;
}
__device__ __forceinline__ float sigm(float x){ return 1.f / (1.f + __expf(-x)); }
__device__ __forceinline__ float softplusf(float x){ return (x > 20.f) ? x : log1pf(__expf(x)); }

__device__ __forceinline__ void gstore(float* p, float v){
  __hip_atomic_store(p, v, __ATOMIC_RELAXED, __HIP_MEMORY_SCOPE_AGENT);
}
__device__ __forceinline__ float gload(const float* p){
  return __hip_atomic_load(p, __ATOMIC_RELAXED, __HIP_MEMORY_SCOPE_AGENT);
}
__device__ __forceinline__ void gstore64(unsigned long long* p, unsigned long long v){
  __hip_atomic_store(p, v, __ATOMIC_RELAXED, __HIP_MEMORY_SCOPE_AGENT);
}
__device__ __forceinline__ unsigned long long gload64(const unsigned long long* p){
  return __hip_atomic_load(p, __ATOMIC_RELAXED, __HIP_MEMORY_SCOPE_AGENT);
}
// lgkmcnt(0)-only barrier: vmcnt=63, expcnt=7, lgkmcnt=0 -> imm 0xC07F
__device__ __forceinline__ void lbar(){
  __builtin_amdgcn_s_waitcnt(0xC07F);
  __builtin_amdgcn_s_barrier();
}

__global__ void __launch_bounds__(NTHR, 1)
ntm_kernel(Params P)
{
  const int b   = blockIdx.x;
  const int tid = threadIdx.x;
  const int wv  = tid >> 6;   // wave 0..7
  const int ln  = tid & 63;

  // ------- inputs (setup_inputs dict order) -------
  const float* inputs  = P.in[0];
  const float* mem0    = P.in[1];
  const float* read_w0 = P.in[2];
  const float* write_w0= P.in[3];
  const float* W_ih = P.in[4];
  const float* W_hh = P.in[5];
  const float* b_ih = P.in[6];
  const float* b_hh = P.in[7];
  const float* Wo   = P.in[8];
  const float* bo   = P.in[9];
  const float* r_Wk = P.in[10]; const float* r_bk = P.in[11];
  const float* r_Wb = P.in[12]; const float* r_bb = P.in[13];
  const float* r_Wg = P.in[14]; const float* r_bg = P.in[15];
  const float* r_Ws = P.in[16]; const float* r_bs = P.in[17];
  const float* r_Wp = P.in[18]; const float* r_bp = P.in[19];
  const float* w_Wk = P.in[20]; const float* w_bk = P.in[21];
  const float* w_Wb = P.in[22]; const float* w_bb = P.in[23];
  const float* w_Wg = P.in[24]; const float* w_bg = P.in[25];
  const float* w_Ws = P.in[26]; const float* w_bs = P.in[27];
  const float* w_Wp = P.in[28]; const float* w_bp = P.in[29];
  const float* w_We = P.in[30]; const float* w_be = P.in[31];
  const float* w_Wa = P.in[32]; const float* w_ba = P.in[33];
  float* out = P.out;

  // ------- global scratch -------
  float* ws    = P.ws;
  float* harr  = ws;                  // 1024 (h double buffer)
  float* keyw  = ws + 1024;           // 256
  float* keyr  = ws + 1280;           // 256
  float* ersv  = ws + 1536;           // 256
  float* addv  = ws + 1792;           // 256
  float* scal  = ws + 2048;           // 16
  float* P0    = ws + 2064;           // 4096
  float* P1    = ws + 6160;           // 4096 (ends 10256)
  unsigned long long* u64b = (unsigned long long*)(ws + 10256); // 8B-aligned
  unsigned long long* pubAC = u64b;                 // 128*PUBSTR
  unsigned long long* pubD  = pubAC + 128*PUBSTR;
  unsigned long long* pubF  = pubD  + 128*PUBSTR;
  unsigned long long* pubH  = pubF  + 128*PUBSTR;
  unsigned long long* pubJ  = pubH  + 128*PUBSTR;
  unsigned long long* wEF = pubJ + 128*PUBSTR;      // 128 each, contiguous
  unsigned long long* wPF = wEF + 128;
  unsigned long long* wEL = wPF + 128;
  unsigned long long* wPL = wEL + 128;
  unsigned long long* rEF = wPL + 128;
  unsigned long long* rPF = rEF + 128;
  unsigned long long* rEL = rPF + 128;
  unsigned long long* rPL = rEL + 128;
  float* Pbuf[2] = { P0, P1 };

  // ------- LDS -------
  __shared__ float s_mem[RPB * Dsz];   // 128KB
  __shared__ float s_co[Hsz];
  __shared__ float s_a[256], s_b[256], s_c[256];
  __shared__ float s_rv[256];
  __shared__ float s_norm[RPB];
  __shared__ float s_e[RPB];
  __shared__ float s_bw[RPB];
  __shared__ float s_rw[RPB];
  __shared__ float s_ww[RPB];
  __shared__ float s_red[8];
  __shared__ float s_lg[16];
  __shared__ float s_wsum[8];
  __shared__ float s_w2[2];
  __shared__ float s_cst[4];
  __shared__ float s_bd[4];
  __shared__ float s_pub;
  __shared__ float s_gval;

  unsigned int ep = 1;

  // pub64 barrier. val = this block's partial; sum -> returns global sum.
  auto gbar = [&](unsigned long long* pub, float val, bool sum, bool fullDrain)->float{
    if (fullDrain) __syncthreads(); else lbar();
    if (tid == 0)
      gstore64(&pub[(size_t)b * PUBSTR],
               ((unsigned long long)ep << 32) | (unsigned long long)__float_as_uint(val));
    if (wv == 0){
      const unsigned long long* p0 = &pub[(size_t)ln * PUBSTR];
      const unsigned long long* p1 = &pub[(size_t)(64 + ln) * PUBSTR];
      unsigned long long k0, k1;
      for (;;){
        k0 = gload64(p0); k1 = gload64(p1);
        bool ok = ((int)((unsigned)(k0 >> 32) - ep) >= 0) &&
                  ((int)((unsigned)(k1 >> 32) - ep) >= 0);
        if (__all(ok)) break;
      }
      if (sum){
        float acc = __uint_as_float((unsigned)k0) + __uint_as_float((unsigned)k1);
        acc = wred64(acc);
        if (ln == 0) s_gval = acc;
      }
    }
    lbar();
    ++ep;
    return s_gval;
  };

  auto bred512 = [&](float v)->float{
    v = wred64(v);
    lbar();
    if (ln == 0) s_red[wv] = v;
    lbar();
    return s_red[0] + s_red[1] + s_red[2] + s_red[3]
         + s_red[4] + s_red[5] + s_red[6] + s_red[7];
  };

  // shift + sharpen; boundaries from s_bd; leaves block partial in s_pub.
  auto shiftSharpen = [&](int si, float* s_prevw, float S){
    float g     = sigm(gload(&scal[si + 1]));
    float gamma = softplusf(gload(&scal[si + 2])) + 1.f;
    float a0 = gload(&scal[si + 3]), a1 = gload(&scal[si + 4]), a2 = gload(&scal[si + 5]);
    float mx = fmaxf(a0, fmaxf(a1, a2));
    float e0 = __expf(a0 - mx), e1 = __expf(a1 - mx), e2 = __expf(a2 - mx);
    float idn = 1.f / (e0 + e1 + e2);
    float s0 = e0 * idn, s1 = e1 * idn, s2 = e2 * idn;
    float invS = 1.f / S;
    float w = 0.f;
    if (tid < RPB){
      float gc = g * invS, gp = 1.f - g;
      float em = s_e[tid],  pm = s_prevw[tid];
      float e1n = (tid < RPB-1) ? s_e[tid+1]     : s_bd[0];
      float p1n = (tid < RPB-1) ? s_prevw[tid+1] : s_bd[1];
      float e2n = (tid > 0)     ? s_e[tid-1]     : s_bd[2];
      float p2n = (tid > 0)     ? s_prevw[tid-1] : s_bd[3];
      float gwm = gc * em  + gp * pm;
      float gw1 = gc * e1n + gp * p1n;   // roll(gw,-1)
      float gw2 = gc * e2n + gp * p2n;   // roll(gw,+1)
      float sh = s0 * gw1 + s1 * gwm + s2 * gw2;
      w = powf(sh, gamma);
      s_bw[tid] = w;
    }
    float tot = wred64(w);
    if (ln == 0 && wv < 2) s_w2[wv] = tot;
    lbar();
    if (tid == 0) s_pub = s_w2[0] + s_w2[1];
  };

  // ------- INIT1: zero parts buffers + h; load persistent weights -------
  {
    if (b < NG && tid < 256){ gstore(&P0[b*256 + tid], 0.f); gstore(&P1[b*256 + tid], 0.f); }
    if (b == 0){ gstore(&harr[tid], 0.f); gstore(&harr[512 + tid], 0.f); }
    if (tid < RPB){
      s_rw[tid] = read_w0[b * RPB + tid];
      s_ww[tid] = write_w0[b * RPB + tid];
    }
    if (tid < 4) s_cst[tid] = 0.f;
  }
  gbar(pubAC, 0.f, false, true);   // ep=1: zeroes drained & visible

  // ------- INIT2: memory rows -> LDS, norms, initial rvec partials into P1 -------
  {
#pragma unroll 1
    for (int it = 0; it < 16; ++it){
      int ml = it * 8 + wv;
      int m  = b * RPB + ml;
      float4 v = *(const float4*)(mem0 + (size_t)m * Dsz + ln * 4);
      *(float4*)(&s_mem[ml * Dsz + ln * 4]) = v;
      float n2 = wred64(v.x*v.x + v.y*v.y + v.z*v.z + v.w*v.w);
      if (ln == 0) s_norm[ml] = sqrtf(n2);
    }
    lbar();
    int col = tid & 255, half = tid >> 8;
    float acc = 0.f;
#pragma unroll 1
    for (int j = half * 64; j < half * 64 + 64; ++j) acc += s_rw[j] * s_mem[j * Dsz + col];
    if (half == 0) s_a[col] = acc;
    lbar();
    if (half == 1) atomicAdd(&P1[(b & (NG-1)) * 256 + col], acc + s_a[col]);
  }
  gbar(pubAC, 0.f, false, true);   // ep=2: atomics drained

  float Srcarry = 1.f;

  // =================== time loop (6 barriers/step) ===================
  for (int t = 0; t < Tlen; ++t){
    const float* hprev = harr + (t & 1) * Hsz;
    float*       hcur  = harr + ((t + 1) & 1) * Hsz;
    const float* xt    = inputs + (size_t)t * Isz;
    float* Pcur = Pbuf[t & 1];          // J(t) writes
    float* Prd  = Pbuf[(t + 1) & 1];    // A(t) reads (J(t-1) / INIT2)

    // ---- A: deferred rw/rvec normalize; LSTM gates ----
    {
      float SrDiv = (t == 0) ? 1.f : (Srcarry + 1e-8f);
      if (t > 0 && tid < RPB) s_rw[tid] = s_bw[tid] / SrDiv;
      s_co[tid] = gload(&hprev[tid]);
      if (tid < 256){
        s_a[tid] = xt[tid];
        float rvv = 0.f;
#pragma unroll
        for (int p = 0; p < NG; ++p) rvv += gload(&Prd[p * 256 + tid]);
        s_rv[tid] = rvv / SrDiv;
      }
      lbar();
      int dd = tid >> 5;          // 0..15: gate = dd>>2, unit = dd&3
      int l  = tid & 31;
      int jj = (b << 2) + (dd & 3);
      int g  = dd >> 2;
      int r  = g * Hsz + jj;
      const float* wi = W_ih + (size_t)r * (Isz + Dsz);
      const float* wh = W_hh + (size_t)r * Hsz;
      float acc = 0.f;
#pragma unroll
      for (int it = 0; it < 4; ++it){
        int k = it * 128 + l * 4;
        float4 a  = *(const float4*)(wi + k);
        float4 xx = (k < Isz) ? *(const float4*)(&s_a[k]) : *(const float4*)(&s_rv[k - Isz]);
        acc += a.x*xx.x + a.y*xx.y + a.z*xx.z + a.w*xx.w;
        float4 hw = *(const float4*)(wh + k);
        float4 hv = *(const float4*)(&s_co[k]);
        acc += hw.x*hv.x + hw.y*hv.y + hw.z*hv.z + hw.w*hv.w;
      }
      acc = wred32(acc);
      if (l == 0) s_lg[dd] = acc + b_ih[r] + b_hh[r];
      lbar();
      if (tid < 4){
        int j = (b << 2) + tid;
        float iv = s_lg[tid], fv = s_lg[4 + tid], gv = s_lg[8 + tid], ov = s_lg[12 + tid];
        float cn = sigm(fv) * s_cst[tid] + sigm(iv) * tanhf(gv);
        s_cst[tid] = cn;
        gstore(&hcur[j], sigm(ov) * tanhf(cn));
      }
    }
    gbar(pubAC, 0.f, false, true);   // h drained

    // ---- C: head projections + output GEMV (balanced slot = q*128+b) ----
    {
      s_co[tid] = gload(&hcur[tid]);
      lbar();
#pragma unroll
      for (int qi = 0; qi < 2; ++qi){
        int q = qi * 8 + wv;          // 0..15
        int slot = q * 128 + b;
        if (q < 11 && slot < 1292){
          const float* Wrow = nullptr; float bias = 0.f; int len = 512;
          float* dst = nullptr; bool act = false; bool plain = false;
          if (slot < 256){ Wrow = w_Wk + (size_t)slot * Hsz; bias = w_bk[slot]; dst = keyw + slot; }
          else if (slot < 512){ int i = slot - 256; Wrow = w_We + (size_t)i * Hsz; bias = w_be[i]; dst = ersv + i; act = true; }
          else if (slot < 768){ int i = slot - 512; Wrow = w_Wa + (size_t)i * Hsz; bias = w_ba[i]; dst = addv + i; }
          else if (slot < 1024){ int i = slot - 768; Wrow = r_Wk + (size_t)i * Hsz; bias = r_bk[i]; dst = keyr + i; }
          else if (slot < 1280){ int i = slot - 1024; Wrow = Wo + (size_t)i * (Hsz + Dsz); bias = bo[i]; len = 768; dst = out + (size_t)t * Isz + i; plain = true; }
          else {
            int i = slot - 1280;
            int ii = (i >= 6) ? i - 6 : i;
            bool rh = (i >= 6);
            const float *Wt, *bt; int row = 0;
            if (ii == 0){ Wt = rh ? r_Wb : w_Wb; bt = rh ? r_bb : w_bb; }
            else if (ii == 1){ Wt = rh ? r_Wg : w_Wg; bt = rh ? r_bg : w_bg; }
            else if (ii == 2){ Wt = rh ? r_Wp : w_Wp; bt = rh ? r_bp : w_bp; }
            else { Wt = rh ? r_Ws : w_Ws; bt = rh ? r_bs : w_bs; row = ii - 3; }
            Wrow = Wt + (size_t)row * Hsz; bias = bt[row]; dst = scal + i;
          }
          float acc = 0.f;
          if (len == 512){
            int k = ln * 8;
            float4 a0 = *(const float4*)(Wrow + k);
            float4 a1 = *(const float4*)(Wrow + k + 4);
            float4 c0 = *(const float4*)(&s_co[k]);
            float4 c1 = *(const float4*)(&s_co[k + 4]);
            acc = a0.x*c0.x + a0.y*c0.y + a0.z*c0.z + a0.w*c0.w
                + a1.x*c1.x + a1.y*c1.y + a1.z*c1.z + a1.w*c1.w;
          } else {
#pragma unroll 1
            for (int kk = ln; kk < 768; kk += 64){
              float xv = (kk < Hsz) ? s_co[kk] : s_rv[kk - Hsz];
              acc += Wrow[kk] * xv;
            }
          }
          acc = wred64(acc);
          if (ln == 0){
            float v = acc + bias;
            if (act) v = sigm(v);
            if (plain) *dst = v; else gstore(dst, v);
          }
        }
      }
    }
    gbar(pubAC, 0.f, false, true);   // projections drained

    // ---- D: write-head content scores; zero next parts buffer; tagged pubs ----
    float S_w;
    {
      float* Pnx = Pbuf[(t + 1) & 1];
      if (b < NG && tid < 256) gstore(&Pnx[b * 256 + tid], 0.f);
      if (tid < 256) s_a[tid] = gload(&keyw[tid]);
      float nk2 = bred512((tid < 256) ? s_a[tid] * s_a[tid] : 0.f);
      float beta  = softplusf(gload(&scal[0]));
      float invbk = beta / fmaxf(sqrtf(nk2), 1e-12f);
      float esum = 0.f;
#pragma unroll 1
      for (int it = 0; it < 16; ++it){
        int ml = it * 8 + wv;
        float4 v  = *(const float4*)(&s_mem[ml * Dsz + ln * 4]);
        float4 kv = *(const float4*)(&s_a[ln * 4]);
        float d = wred64(v.x*kv.x + v.y*kv.y + v.z*kv.z + v.w*kv.w);
        float score = d * invbk / fmaxf(s_norm[ml], 1e-12f);
        float e = __expf(score - beta);
        if (ln == 0){ s_e[ml] = e; esum += e; }
      }
      if (ln == 0) s_wsum[wv] = esum;
      lbar();
      if (tid == 0){
        float tot = 0.f;
#pragma unroll
        for (int k = 0; k < 8; ++k) tot += s_wsum[k];
        s_pub = tot;
        unsigned long long tg = ((unsigned long long)ep << 32);
        gstore64(&wEF[b], tg | (unsigned long long)__float_as_uint(s_e[0]));
        gstore64(&wPF[b], tg | (unsigned long long)__float_as_uint(s_ww[0]));
        gstore64(&wEL[b], tg | (unsigned long long)__float_as_uint(s_e[RPB-1]));
        gstore64(&wPL[b], tg | (unsigned long long)__float_as_uint(s_ww[RPB-1]));
      }
      S_w = gbar(pubD, s_pub, true, false);   // no drain: all outputs tagged
    }

    // ---- F: write-head shift+sharpen; prefetch H inputs with waves 4-7 ----
    float Sw;
    {
      unsigned want = ep - 1;
      if (wv == 0 && ln < 4){
        unsigned long long* bp = (ln == 0) ? &wEF[(b + 1) & (NBLK-1)]
                               : (ln == 1) ? &wPF[(b + 1) & (NBLK-1)]
                               : (ln == 2) ? &wEL[(b - 1) & (NBLK-1)]
                                           : &wPL[(b - 1) & (NBLK-1)];
        unsigned long long k;
        do { k = gload64(bp); } while ((int)((unsigned)(k >> 32) - want) < 0);
        s_bd[ln] = __uint_as_float((unsigned)k);
      }
      if (wv >= 4){
        int i = tid - 256;
        s_a[i] = gload(&ersv[i]); s_b[i] = gload(&addv[i]); s_c[i] = gload(&keyr[i]);
      }
      lbar();
      shiftSharpen(0, s_ww, S_w);
      Sw = gbar(pubF, s_pub, true, false);
    }

    // ---- H: normalize ww, memory update, new norms + read scores ----
    float S_r;
    {
      float nk2 = bred512((tid < 256) ? s_c[tid] * s_c[tid] : 0.f);
      float beta  = softplusf(gload(&scal[6]));
      float invbk = beta / fmaxf(sqrtf(nk2), 1e-12f);
      float invSw = 1.f / (Sw + 1e-8f);
      if (tid < RPB) s_ww[tid] = s_bw[tid] * invSw;
      float esum = 0.f;
#pragma unroll 1
      for (int it = 0; it < 16; ++it){
        int ml = it * 8 + wv;
        float wwm = s_bw[ml] * invSw;
        int off = ml * Dsz + ln * 4;
        float4 mv = *(const float4*)(&s_mem[off]);
        float4 er = *(const float4*)(&s_a[ln * 4]);
        float4 ad = *(const float4*)(&s_b[ln * 4]);
        float4 kr = *(const float4*)(&s_c[ln * 4]);
        float4 nv;
        nv.x = mv.x * (1.f - wwm * er.x) + wwm * ad.x;
        nv.y = mv.y * (1.f - wwm * er.y) + wwm * ad.y;
        nv.z = mv.z * (1.f - wwm * er.z) + wwm * ad.z;
        nv.w = mv.w * (1.f - wwm * er.w) + wwm * ad.w;
        *(float4*)(&s_mem[off]) = nv;
        float n2 = nv.x*nv.x + nv.y*nv.y + nv.z*nv.z + nv.w*nv.w;
        float dt = nv.x*kr.x + nv.y*kr.y + nv.z*kr.z + nv.w*kr.w;
        n2 = wred64(n2);
        dt = wred64(dt);
        float nr = sqrtf(n2);
        if (ln == 0) s_norm[ml] = nr;
        float score = dt * invbk / fmaxf(nr, 1e-12f);
        float e = __expf(score - beta);
        if (ln == 0){ s_e[ml] = e; esum += e; }
      }
      if (ln == 0) s_wsum[wv] = esum;
      lbar();
      if (tid == 0){
        float tot = 0.f;
#pragma unroll
        for (int k = 0; k < 8; ++k) tot += s_wsum[k];
        s_pub = tot;
        unsigned long long tg = ((unsigned long long)ep << 32);
        gstore64(&rEF[b], tg | (unsigned long long)__float_as_uint(s_e[0]));
        gstore64(&rPF[b], tg | (unsigned long long)__float_as_uint(s_rw[0]));
        gstore64(&rEL[b], tg | (unsigned long long)__float_as_uint(s_e[RPB-1]));
        gstore64(&rPL[b], tg | (unsigned long long)__float_as_uint(s_rw[RPB-1]));
      }
      S_r = gbar(pubH, s_pub, true, false);
    }

    // ---- J: read-head shift+sharpen; UNNORMALIZED rvec partials (atomics) ----
    {
      unsigned want = ep - 1;
      if (wv == 0 && ln < 4){
        unsigned long long* bp = (ln == 0) ? &rEF[(b + 1) & (NBLK-1)]
                               : (ln == 1) ? &rPF[(b + 1) & (NBLK-1)]
                               : (ln == 2) ? &rEL[(b - 1) & (NBLK-1)]
                                           : &rPL[(b - 1) & (NBLK-1)];
        unsigned long long k;
        do { k = gload64(bp); } while ((int)((unsigned)(k >> 32) - want) < 0);
        s_bd[ln] = __uint_as_float((unsigned)k);
      }
      lbar();
      shiftSharpen(6, s_rw, S_r);
      lbar();
      int col = tid & 255, half = tid >> 8;
      float acc = 0.f;
#pragma unroll 1
      for (int j = half * 64; j < half * 64 + 64; ++j) acc += s_bw[j] * s_mem[j * Dsz + col];
      if (half == 0) s_a[col] = acc;
      lbar();
      if (half == 1) atomicAdd(&Pcur[(b & (NG-1)) * 256 + col], acc + s_a[col]);
      Srcarry = gbar(pubJ, s_pub, true, true);   // full drain: atomics before pub
    }
  }
}

extern "C" void kernel_launch(void* const* d_in, const int* in_sizes, int n_in,
                              void* d_out, int out_size, void* d_ws, size_t ws_size,
                              hipStream_t stream)
{
  (void)in_sizes; (void)out_size;
  if (n_in < 34) return;
  if (ws_size < (size_t)98304) return;   // ~90KB scratch needed
  Params P;
  for (int i = 0; i < 34; ++i) P.in[i] = (const float*)d_in[i];
  P.out = (float*)d_out;
  P.ws  = (float*)d_ws;
  hipLaunchKernelGGL(ntm_kernel, dim3(NBLK), dim3(NTHR), 0, stream, P);
}